// Round 14
// baseline (115.051 us; speedup 1.0000x reference)
//
#include <hip/hip_runtime.h>

// LDS forward collapsed to causal conv:
//   y[b,t,o] = sum_{d<=t} x[b,t-d] * K[d,o] + G[t,o]
//   K[d,o] = sum_s C[s,o] A[s]^d B[s]  (+ M[o,0,d-1] for d in 1..5)
//   G[t,o] = sum_s C[s,o] A[s]^{t+1} h0[s]
//
// R14: NO LDS, NO BARRIERS in k_main. R12/R13 showed the ~26us gap over the
// MFMA floor == the LDS instruction pipe (8 waves x ~38 ds_read_b128 x 12cy
// per batch, serial with MFMA). A-frags now come straight from global XOCT:
// the per-block window is ~4.5KB -> L1-resident, served by the near-idle
// VMEM pipe. 8-slot rolling window, refills 2.5 steps ahead. Next-batch
// window init is issued BEFORE the epilogue stores (older in vmcnt order ->
// store drain never blocks the loads). acc inits from the register G tile.
// 512 blocks x 256 thr (2/CU), wave = 64t x 32o, NB=16 batches per block.

typedef __attribute__((ext_vector_type(8))) short short8v;
typedef __attribute__((ext_vector_type(4))) float float4v;

#define NB 16

static __device__ __forceinline__ unsigned short f2bf(float f) {
    union { float f; unsigned int u; } x; x.f = f;
    unsigned int r = x.u + 0x7fffu + ((x.u >> 16) & 1u);  // RNE
    return (unsigned short)(r >> 16);
}

// ---------------- prep: KT/G (blocks 0..1023) + XOCT (blocks 1024..1279) ---
__global__ __launch_bounds__(256) void k_prep(const float* __restrict__ A,
                                              const float* __restrict__ B,
                                              const float* __restrict__ h0,
                                              const float* __restrict__ C,
                                              const float* __restrict__ M,
                                              const float* __restrict__ x,
                                              unsigned short* __restrict__ KT,
                                              float* __restrict__ G,
                                              short8v* __restrict__ XOCT) {
    __shared__ float PBL[512][4];
    __shared__ float PHL[512][4];
    __shared__ float red[4][64][8];
    __shared__ unsigned short xs[512];
    const int tid = threadIdx.x;

    if (blockIdx.x < 1024) {
        const int d0 = (blockIdx.x & 127) * 4;
        const int oc = blockIdx.x >> 7;

        #pragma unroll
        for (int q = 0; q < 2; ++q) {
            int ss = tid + q * 256;
            float a = A[ss];
            float r = 1.0f, base = a;
            #pragma unroll
            for (int bit = 0; bit < 9; ++bit) {
                if (d0 & (1 << bit)) r *= base;
                base *= base;
            }
            float bs = B[ss], hs = h0[ss];
            #pragma unroll
            for (int j = 0; j < 4; ++j) {
                PBL[ss][j] = r * bs;
                PHL[ss][j] = r * a * hs;
                r *= a;
            }
        }
        __syncthreads();

        const int lane = tid & 63;
        const int sc   = tid >> 6;
        const int o    = oc * 64 + lane;
        float kt[4] = {0.f, 0.f, 0.f, 0.f};
        float gg[4] = {0.f, 0.f, 0.f, 0.f};
        for (int si = 0; si < 128; si += 8) {
            float c8[8];
            #pragma unroll
            for (int u = 0; u < 8; ++u)
                c8[u] = C[(sc * 128 + si + u) * 512 + o];
            #pragma unroll
            for (int u = 0; u < 8; ++u) {
                int s = sc * 128 + si + u;
                #pragma unroll
                for (int j = 0; j < 4; ++j) {
                    kt[j] = fmaf(PBL[s][j], c8[u], kt[j]);
                    gg[j] = fmaf(PHL[s][j], c8[u], gg[j]);
                }
            }
        }
        #pragma unroll
        for (int j = 0; j < 4; ++j) {
            red[sc][lane][j]     = kt[j];
            red[sc][lane][j + 4] = gg[j];
        }
        __syncthreads();
        if (sc == 0) {
            #pragma unroll
            for (int j = 0; j < 4; ++j) {
                float v  = red[0][lane][j] + red[1][lane][j]
                         + red[2][lane][j] + red[3][lane][j];
                float gv = red[0][lane][j+4] + red[1][lane][j+4]
                         + red[2][lane][j+4] + red[3][lane][j+4];
                int d = d0 + j;
                if (d >= 1 && d <= 5) v += M[o * 5 + (d - 1)];
                KT[o * 512 + d] = f2bf(v);
                G[d * 512 + o]  = gv;
            }
        }
    } else {
        // xprep: unpadded reversed-octet table, 1024 entries per batch
        const int b = blockIdx.x - 1024;
        #pragma unroll
        for (int q = 0; q < 2; ++q) {
            int i = tid * 2 + q;
            xs[i] = f2bf(x[b * 512 + 511 - i]);
        }
        __syncthreads();
        short8v* dst = XOCT + (size_t)b * 1024;
        #pragma unroll
        for (int q = 0; q < 4; ++q) {
            int e = tid * 4 + q;
            short8v v;
            #pragma unroll
            for (int jj = 0; jj < 8; ++jj) {
                int i = e + jj;
                v[jj] = (i < 512) ? (short)xs[i] : (short)0;
            }
            dst[e] = v;
        }
    }
}

// ---------------- main: 512 blocks x 256 thr, no LDS, no barriers ----------
__global__ __launch_bounds__(256, 2) void k_main(const short8v* __restrict__ XOCT,
                                                 const unsigned short* __restrict__ KT,
                                                 const float* __restrict__ G,
                                                 float* __restrict__ out) {
    const int bo0 = blockIdx.x * 32;    // 16 o-chunks
    const int bt0 = blockIdx.y * 256;   // 2 t-halves
    const int b0  = blockIdx.z * NB;    // 16 batch-groups
    const int tid  = threadIdx.x;
    const int lane = tid & 63;
    const int wv   = tid >> 6;          // 0..3 -> 64t chunk
    const int t0w  = bt0 + wv * 64;
    const int lrow = lane & 15;
    const int g    = lane >> 4;

    // batch-invariant: B-slice (128 VGPR) + G tile (32 VGPR), loaded once
    short8v bfr[2][16];
    #pragma unroll
    for (int ni = 0; ni < 2; ++ni) {
        const unsigned short* bp = KT + (bo0 + ni * 16 + lrow) * 512 + g * 8;
        #pragma unroll
        for (int ks = 0; ks < 16; ++ks)
            bfr[ni][ks] = *(const short8v*)(bp + ks * 32);
    }
    float4v gacc[4][2];
    #pragma unroll
    for (int mi = 0; mi < 4; ++mi)
        #pragma unroll
        for (int ni = 0; ni < 2; ++ni)
            gacc[mi][ni] = *(const float4v*)(G + (t0w + mi * 16 + lrow) * 512
                                               + bo0 + ni * 16 + g * 4);

    // A-window base: frag j lives at xw[16*j] (entry E0 + 16j), L1-resident
    const int E0 = 511 - t0w - lrow + 8 * g;        // in [48, 535]
    const short8v* xw = XOCT + (size_t)b0 * 1024 + E0;

    short8v aw[8];
    #pragma unroll
    for (int j = -3; j <= 4; ++j)
        aw[j & 7] = xw[16 * j];

    for (int bi = 0; bi < NB; ++bi) {
        float4v acc[4][2];
        #pragma unroll
        for (int mi = 0; mi < 4; ++mi)
            #pragma unroll
            for (int ni = 0; ni < 2; ++ni)
                acc[mi][ni] = gacc[mi][ni];         // G folded into C-init

        __builtin_amdgcn_s_setprio(1);
        #pragma unroll
        for (int ks = 0; ks < 16; ++ks) {
            acc[3][0] = __builtin_amdgcn_mfma_f32_16x16x32_bf16(
                bfr[0][ks], aw[(2 * ks - 3) & 7], acc[3][0], 0, 0, 0);
            acc[3][1] = __builtin_amdgcn_mfma_f32_16x16x32_bf16(
                bfr[1][ks], aw[(2 * ks - 3) & 7], acc[3][1], 0, 0, 0);
            acc[2][0] = __builtin_amdgcn_mfma_f32_16x16x32_bf16(
                bfr[0][ks], aw[(2 * ks - 2) & 7], acc[2][0], 0, 0, 0);
            acc[2][1] = __builtin_amdgcn_mfma_f32_16x16x32_bf16(
                bfr[1][ks], aw[(2 * ks - 2) & 7], acc[2][1], 0, 0, 0);
            if (ks <= 12) {   // refill 2.5 steps ahead (consumed at ks+3/ks+4)
                aw[(2 * ks + 5) & 7] = xw[16 * (2 * ks + 5)];
                aw[(2 * ks + 6) & 7] = xw[16 * (2 * ks + 6)];
            }
            acc[1][0] = __builtin_amdgcn_mfma_f32_16x16x32_bf16(
                bfr[0][ks], aw[(2 * ks - 1) & 7], acc[1][0], 0, 0, 0);
            acc[1][1] = __builtin_amdgcn_mfma_f32_16x16x32_bf16(
                bfr[1][ks], aw[(2 * ks - 1) & 7], acc[1][1], 0, 0, 0);
            acc[0][0] = __builtin_amdgcn_mfma_f32_16x16x32_bf16(
                bfr[0][ks], aw[(2 * ks) & 7], acc[0][0], 0, 0, 0);
            acc[0][1] = __builtin_amdgcn_mfma_f32_16x16x32_bf16(
                bfr[1][ks], aw[(2 * ks) & 7], acc[0][1], 0, 0, 0);
        }
        __builtin_amdgcn_s_setprio(0);

        // issue next batch's window init BEFORE this batch's stores, so the
        // loads are OLDER in vmcnt order and never wait on the store drain.
        if (bi + 1 < NB) {
            xw += 1024;
            #pragma unroll
            for (int j = -3; j <= 4; ++j)
                aw[j & 7] = xw[16 * j];
        }

        // epilogue: pure stores (G already in acc)
        float* op = out + (size_t)(b0 + bi) * 262144;
        #pragma unroll
        for (int mi = 0; mi < 4; ++mi) {
            const int t = t0w + mi * 16 + lrow;
            float* rp = op + t * 512 + bo0 + g * 4;
            *(float4v*)(rp)      = acc[mi][0];
            *(float4v*)(rp + 16) = acc[mi][1];
        }
    }
}

extern "C" void kernel_launch(void* const* d_in, const int* in_sizes, int n_in,
                              void* d_out, int out_size, void* d_ws, size_t ws_size,
                              hipStream_t stream) {
    const float* x  = (const float*)d_in[0];   // [256,512,1]
    const float* A  = (const float*)d_in[1];   // [512]
    const float* B  = (const float*)d_in[2];   // [1,512]
    const float* C  = (const float*)d_in[3];   // [512,512]
    const float* M  = (const float*)d_in[4];   // [512,1,5]
    const float* h0 = (const float*)d_in[5];   // [512]
    float* out = (float*)d_out;

    char* ws = (char*)d_ws;
    unsigned short* KT   = (unsigned short*)ws;                      // 512 KB
    float*          G    = (float*)(ws + (1u << 19));                // 1 MB
    short8v*        XOCT = (short8v*)(ws + (1u << 19) + (1u << 20)); // 4 MB

    k_prep<<<1280, 256, 0, stream>>>(A, B, h0, C, M, x, KT, G, XOCT);
    k_main<<<dim3(16, 2, 16), 256, 0, stream>>>(XOCT, KT, G, out);
}